// Round 17
// baseline (295.809 us; speedup 1.0000x reference)
//
#include <hip/hip_runtime.h>
#include <math.h>

typedef __attribute__((ext_vector_type(8))) short bf16x8;
typedef __attribute__((ext_vector_type(4))) float f32x4;

__device__ __forceinline__ unsigned short f2bf(float x) {
  union { float f; unsigned int u; } v; v.f = x;
  unsigned int r = v.u + 0x7fffu + ((v.u >> 16) & 1u);
  return (unsigned short)(r >> 16);
}
__device__ __forceinline__ float bf2f(unsigned short b) {
  union { unsigned int u; float f; } v; v.u = ((unsigned int)b) << 16; return v.f;
}
__device__ __forceinline__ void split2(float x, unsigned short& h, unsigned short& l) {
  h = f2bf(x);
  l = f2bf(x - bf2f(h));
}
__device__ __forceinline__ int fsi(int q, int c) { return q * 256 + (c ^ ((q & 7) << 2)); }

// direct write into coalesced slot layout: [pair][slot(32)][lane(64)][8us]
__device__ __forceinline__ void writeP(unsigned short* __restrict__ P, int col, int k,
                                       unsigned short h, unsigned short l) {
  int tile = col >> 4;
  int lane = (((k >> 3) & 3) << 4) | (col & 15);
  int ks = k >> 5, j8 = k & 7;
  size_t base = ((size_t)(tile >> 1) * 16384) + (size_t)(((tile & 1) << 4) + ks * 2) * 512
              + (size_t)lane * 8 + j8;
  P[base] = h;
  P[base + 512] = l;
}

// 16 WAVE-COALESCED loads + terminal vmcnt(0) (drains ALL outstanding vmem).
__device__ __forceinline__ void ld16(const unsigned short* b, bf16x8* f) {
  const unsigned short* b1 = b + 2048;
  const unsigned short* b2 = b + 4096;
  const unsigned short* b3 = b + 6144;
  asm volatile(
    "global_load_dwordx4 %0, %16, off\n\t"
    "global_load_dwordx4 %1, %16, off offset:1024\n\t"
    "global_load_dwordx4 %2, %16, off offset:2048\n\t"
    "global_load_dwordx4 %3, %16, off offset:3072\n\t"
    "global_load_dwordx4 %4, %17, off\n\t"
    "global_load_dwordx4 %5, %17, off offset:1024\n\t"
    "global_load_dwordx4 %6, %17, off offset:2048\n\t"
    "global_load_dwordx4 %7, %17, off offset:3072\n\t"
    "global_load_dwordx4 %8, %18, off\n\t"
    "global_load_dwordx4 %9, %18, off offset:1024\n\t"
    "global_load_dwordx4 %10, %18, off offset:2048\n\t"
    "global_load_dwordx4 %11, %18, off offset:3072\n\t"
    "global_load_dwordx4 %12, %19, off\n\t"
    "global_load_dwordx4 %13, %19, off offset:1024\n\t"
    "global_load_dwordx4 %14, %19, off offset:2048\n\t"
    "global_load_dwordx4 %15, %19, off offset:3072\n\t"
    "s_waitcnt vmcnt(0)"
    : "=&v"(f[0]), "=&v"(f[1]), "=&v"(f[2]), "=&v"(f[3]),
      "=&v"(f[4]), "=&v"(f[5]), "=&v"(f[6]), "=&v"(f[7]),
      "=&v"(f[8]), "=&v"(f[9]), "=&v"(f[10]), "=&v"(f[11]),
      "=&v"(f[12]), "=&v"(f[13]), "=&v"(f[14]), "=&v"(f[15])
    : "v"(b), "v"(b1), "v"(b2), "v"(b3));
}

// Same 16 loads, NO wait: valid only after a later ld16's vmcnt(0) + sched_barrier(0).
__device__ __forceinline__ void ld16nw(const unsigned short* b, bf16x8* f) {
  const unsigned short* b1 = b + 2048;
  const unsigned short* b2 = b + 4096;
  const unsigned short* b3 = b + 6144;
  asm volatile(
    "global_load_dwordx4 %0, %16, off\n\t"
    "global_load_dwordx4 %1, %16, off offset:1024\n\t"
    "global_load_dwordx4 %2, %16, off offset:2048\n\t"
    "global_load_dwordx4 %3, %16, off offset:3072\n\t"
    "global_load_dwordx4 %4, %17, off\n\t"
    "global_load_dwordx4 %5, %17, off offset:1024\n\t"
    "global_load_dwordx4 %6, %17, off offset:2048\n\t"
    "global_load_dwordx4 %7, %17, off offset:3072\n\t"
    "global_load_dwordx4 %8, %18, off\n\t"
    "global_load_dwordx4 %9, %18, off offset:1024\n\t"
    "global_load_dwordx4 %10, %18, off offset:2048\n\t"
    "global_load_dwordx4 %11, %18, off offset:3072\n\t"
    "global_load_dwordx4 %12, %19, off\n\t"
    "global_load_dwordx4 %13, %19, off offset:1024\n\t"
    "global_load_dwordx4 %14, %19, off offset:2048\n\t"
    "global_load_dwordx4 %15, %19, off offset:3072"
    : "=&v"(f[0]), "=&v"(f[1]), "=&v"(f[2]), "=&v"(f[3]),
      "=&v"(f[4]), "=&v"(f[5]), "=&v"(f[6]), "=&v"(f[7]),
      "=&v"(f[8]), "=&v"(f[9]), "=&v"(f[10]), "=&v"(f[11]),
      "=&v"(f[12]), "=&v"(f[13]), "=&v"(f[14]), "=&v"(f[15])
    : "v"(b), "v"(b1), "v"(b2), "v"(b3));
}

#define MFMA(a, b, c) __builtin_amdgcn_mfma_f32_16x16x32_bf16(a, b, c, 0, 0, 0)

// ---- 64-row GEMM helpers ----
__device__ __forceinline__ void gemm2t64(
    const unsigned short* __restrict__ Wp, int tile0,
    int lane, int lk, int l15,
    const unsigned short (&AS)[2][32][64][8], f32x4 (&acc)[2][4])
{
  const unsigned short* base = Wp + ((size_t)(tile0 >> 1) * 16384) + (size_t)lane * 8;
  bf16x8 f[32];
  ld16nw(base, f);
  ld16(base + 8192, f + 16);   // vmcnt(0) drains both batches
  __builtin_amdgcn_sched_barrier(0);
#pragma unroll
  for (int ks = 0; ks < 8; ++ks) {
    bf16x8 h0 = f[2 * ks], l0 = f[2 * ks + 1];
    bf16x8 h1 = f[16 + 2 * ks], l1 = f[17 + 2 * ks];
#pragma unroll
    for (int nf = 0; nf < 4; ++nf) {
      bf16x8 bqh = *(const bf16x8*)&AS[0][ks * 4 + lk][nf * 16 + l15][0];
      bf16x8 bql = *(const bf16x8*)&AS[1][ks * 4 + lk][nf * 16 + l15][0];
      acc[0][nf] = MFMA(h0, bqh, acc[0][nf]);
      acc[0][nf] = MFMA(h0, bql, acc[0][nf]);
      acc[0][nf] = MFMA(l0, bqh, acc[0][nf]);
      acc[1][nf] = MFMA(h1, bqh, acc[1][nf]);
      acc[1][nf] = MFMA(h1, bql, acc[1][nf]);
      acc[1][nf] = MFMA(l1, bqh, acc[1][nf]);
    }
  }
}

__device__ __forceinline__ void gemm1t64(
    const unsigned short* __restrict__ Wp, int tile,
    int lane, int lk, int l15,
    const unsigned short (&AS)[2][32][64][8], f32x4 (&acc)[4])
{
  const unsigned short* base = Wp + ((size_t)(tile >> 1) * 16384) + (size_t)(tile & 1) * 8192 + (size_t)lane * 8;
  bf16x8 f[16];
  ld16(base, f);
  __builtin_amdgcn_sched_barrier(0);
#pragma unroll
  for (int ks = 0; ks < 8; ++ks) {
    bf16x8 eh = f[2 * ks], el = f[2 * ks + 1];
#pragma unroll
    for (int nf = 0; nf < 4; ++nf) {
      bf16x8 bqh = *(const bf16x8*)&AS[0][ks * 4 + lk][nf * 16 + l15][0];
      bf16x8 bql = *(const bf16x8*)&AS[1][ks * 4 + lk][nf * 16 + l15][0];
      acc[nf] = MFMA(eh, bqh, acc[nf]);
      acc[nf] = MFMA(eh, bql, acc[nf]);
      acc[nf] = MFMA(el, bqh, acc[nf]);
    }
  }
}

// ---------------- pooling (2x2 mean) ----------------
__global__ __launch_bounds__(256) void pool2x2(const float* __restrict__ in, float* __restrict__ out,
                                               int h, int w, int total)
{
  int i = blockIdx.x * 256 + threadIdx.x;
  if (i >= total) return;
  int x = i % w; int r = i / w; int y = r % h; int ci = r / h;
  const float* p = in + (size_t)ci * (4 * h * w) + (size_t)(2 * y) * (2 * w) + 2 * x;
  out[i] = (p[0] + p[1] + p[2 * w] + p[2 * w + 1]) * 0.25f;
}

// ---------------- merged pool-level1 + weight prep ----------------
__global__ __launch_bounds__(256) void pp(
    const float* __restrict__ imgs, float* __restrict__ cur1,
    const float* __restrict__ wo, const float* __restrict__ bo,
    const float* __restrict__ wa, const float* __restrict__ ba,
    const float* __restrict__ wout, const float* __restrict__ wts1, const float* __restrict__ wts2,
    const float* __restrict__ wfpn, const float* __restrict__ wval,
    const float* __restrict__ cams, const float* __restrict__ lev,
    const float* __restrict__ bfpn, const float* __restrict__ bval,
    unsigned short* __restrict__ wcatP, float* __restrict__ bcat,
    unsigned short* __restrict__ woutP, unsigned short* __restrict__ wts1P,
    unsigned short* __restrict__ w45P, unsigned short* __restrict__ wcombP,
    float* __restrict__ e2)
{
  int blk = blockIdx.x, t = threadIdx.x;
  if (blk < 8448) { // pool level 1: imgs -> cur1 (h=16,w=44)
    int i = blk * 256 + t;
    if (i >= 2162688) return;
    const int h = 16, w = 44;
    int x = i % w; int r = i / w; int y = r % h; int ci = r / h;
    const float* p = imgs + (size_t)ci * (4 * h * w) + (size_t)(2 * y) * (2 * w) + 2 * x;
    cur1[i] = (p[0] + p[1] + p[2 * w] + p[2 * w + 1]) * 0.25f;
    return;
  }
  int bb = blk - 8448;
  if (bb < 768) { // wcomb[l][i][j] = (wfpn[l]@wval)[i][j]; store col=l*256+j, k=i
    int l = bb >> 8, i = bb & 255, j = t;
    const float* a = wfpn + ((size_t)l * 256 + i) * 256;
    float acc = 0.f;
    for (int k = 0; k < 256; ++k) acc = fmaf(a[k], wval[(size_t)k * 256 + j], acc);
    unsigned short h, lo; split2(acc, h, lo);
    writeP(wcombP, l * 256 + j, i, h, lo);
  } else if (bb < 1056) { // wcat col c, k
    int i = (bb - 768) * 256 + t;
    int c = i >> 8, k = i & 255;
    float v = (c < 192) ? wo[k * 192 + c] : wa[k * 96 + (c - 192)];
    unsigned short h, l; split2(v, h, l);
    writeP(wcatP, c, k, h, l);
    if (i < 288) bcat[i] = (i < 192) ? bo[i] : ba[i - 192];
  } else if (bb < 1312) { // wout^T
    int i = (bb - 1056) * 256 + t;
    int nn = i >> 8, k = i & 255;
    float v = wout[(size_t)k * 256 + nn];
    unsigned short h, l; split2(v, h, l);
    writeP(woutP, nn, k, h, l);
  } else if (bb < 1568) { // wts1^T
    int i = (bb - 1312) * 256 + t;
    int nn = i >> 8, k = i & 255;
    float v = wts1[(size_t)k * 256 + nn];
    unsigned short h, l; split2(v, h, l);
    writeP(wts1P, nn, k, h, l);
  } else if (bb < 1824) { // w45 cols 0..255 = wts2^T
    int i = (bb - 1568) * 256 + t;
    int nn = i >> 8, k = i & 255;
    float v = wts2[(size_t)k * 256 + nn];
    unsigned short h, l; split2(v, h, l);
    writeP(w45P, nn, k, h, l);
  } else if (bb < 2112) { // w45 cols 256..543 = (wts2 @ wcat)^T
    int mp = bb - 1824; // 0..287
    int k = t;
    float acc = 0.f;
    for (int j = 0; j < 256; ++j) {
      float wc = (mp < 192) ? wo[j * 192 + mp] : wa[j * 96 + (mp - 192)];
      acc = fmaf(wts2[(size_t)k * 256 + j], wc, acc);
    }
    unsigned short h, l; split2(acc, h, l);
    writeP(w45P, 256 + mp, k, h, l);
  } else { // e2
    int e = bb - 2112;
    int n = e / 3, l = e % 3, j = t;
    float acc = bval[j];
    for (int k = 0; k < 256; ++k) {
      float s = cams[n * 256 + k] + lev[l * 256 + k] + bfpn[l * 256 + k];
      acc = fmaf(s, wval[(size_t)k * 256 + j], acc);
    }
    e2[(size_t)e * 256 + j] = acc;
  }
}

// ---------------- merged value (64 pos/block, z<2) + init (z==2) ----------------
__global__ __launch_bounds__(512) void vi_fused(
    const float* __restrict__ imgs, const float* __restrict__ cur1a, const float* __restrict__ cur2a,
    const unsigned short* __restrict__ wcombP, const float* __restrict__ e2,
    float* __restrict__ Vall,
    const float* __restrict__ bev_pos, const float* __restrict__ bev_query,
    const float* __restrict__ bts2,
    const unsigned short* __restrict__ wcatP, const float* __restrict__ bcat,
    float* __restrict__ posA, float* __restrict__ posB,
    float* __restrict__ qtmpA, float* __restrict__ qtmpB)
{
  __shared__ __align__(16) unsigned short AS[2][32][64][8];  // 64 KB
  float* ASf = (float*)(&AS[0][0][0][0]);
  int t = threadIdx.x, wid = t >> 6, lane = t & 63, l15 = lane & 15, lk = lane >> 4;
  f32x4 zed = {0.f, 0.f, 0.f, 0.f};

  if (blockIdx.z < 2) {
    // ================= VALUE path (64 positions/block) =================
    int bx = blockIdx.x, cam = blockIdx.y, bz = blockIdx.z;
    const float* img0 = imgs + (size_t)bz * 4325376;
    const float* cur1 = cur1a + (size_t)bz * 1081344;
    const float* cur2 = cur2a + (size_t)bz * 270336;
    float* V = Vall + (size_t)bz * 5677056;
    int level, tb, hw; const float* src;
    if (bx < 44)      { level = 0; tb = bx;      hw = 2816; src = img0; }
    else if (bx < 55) { level = 1; tb = bx - 44; hw = 704;  src = cur1; }
    else              { level = 2; tb = bx - 55; hw = 176;  src = cur2; }
    int p0 = tb * 64;
    const int LST[3] = {0, 2816, 3520};
    src += (size_t)cam * 256 * hw;

    { // stage: coalesced scalar reads down k-columns, vector bf16x8 LDS writes
      int pos = t & 63, kg = t >> 6;   // kg 0..7, 32 k each
      bool ok = (p0 + pos) < hw;
      const float* col = src + p0 + pos;
      float vals[32];
#pragma unroll
      for (int i = 0; i < 32; ++i) {
        int k = kg * 32 + i;
        vals[i] = ok ? col[(size_t)k * hw] : 0.f;
      }
#pragma unroll
      for (int qt = 0; qt < 4; ++qt) {
        int ch = kg * 4 + qt;
        bf16x8 hv, lv;
#pragma unroll
        for (int j = 0; j < 8; ++j) {
          unsigned short h, l; split2(vals[qt * 8 + j], h, l);
          hv[j] = (short)h; lv[j] = (short)l;
        }
        *(bf16x8*)&AS[0][ch][pos][0] = hv;
        *(bf16x8*)&AS[1][ch][pos][0] = lv;
      }
    }
    __syncthreads();

    f32x4 acc[2][4] = {{zed, zed, zed, zed}, {zed, zed, zed, zed}};
    gemm2t64(wcombP, level * 16 + wid * 2, lane, lk, l15, AS, acc);
    __syncthreads();

    const float* bias = e2 + (size_t)(cam * 3 + level) * 256;
#pragma unroll
    for (int mf = 0; mf < 2; ++mf) {
      int chb = (wid * 2 + mf) * 16 + lk * 4;
      float4 b4 = *(const float4*)(bias + chb);
#pragma unroll
      for (int nf = 0; nf < 4; ++nf) {
        int q = nf * 16 + l15;
        float4 o;
        o.x = acc[mf][nf][0] + b4.x; o.y = acc[mf][nf][1] + b4.y;
        o.z = acc[mf][nf][2] + b4.z; o.w = acc[mf][nf][3] + b4.w;
        *(float4*)&ASf[fsi(q, chb)] = o;
      }
    }
    __syncthreads();
    float* Vb = V + ((size_t)cam * 3696 + LST[level] + p0) * 256;
#pragma unroll
    for (int j = 0; j < 8; ++j) {
      int g = t + j * 512;
      int q = g >> 6, c = (g & 63) * 4;
      if (p0 + q < hw)
        *(float4*)(Vb + (size_t)q * 256 + c) = *(const float4*)&ASf[fsi(q, c)];
    }
    return;
  }

  // ================= INIT path (z == 2): id = by*58+bx in [0,314) =================
  {
    int id = blockIdx.y * 58 + blockIdx.x;
    if (id >= 314) return;
    int r0 = (id >> 1) * 64;
    int y = id & 1;
    const float* base = y ? bev_query : bev_pos;
    const float* padd = y ? bev_pos : nullptr;
    const float* rb = y ? nullptr : bts2;
    float* oA = y ? qtmpA : posA;
    float* oB = y ? qtmpB : posB;

#pragma unroll
    for (int j = 0; j < 8; ++j) {
      int g = t + j * 512;
      int q = g >> 6, c = (g & 63) * 4;
      int rq = r0 + q; if (rq > 9999) rq = 9999;
      float4 a = *(const float4*)(base + (size_t)rq * 256 + c);
      if (padd) {
        float4 p = *(const float4*)(padd + (size_t)rq * 256 + c);
        a.x += p.x; a.y += p.y; a.z += p.z; a.w += p.w;
      }
      if (rb) {
        float4 rv = *(const float4*)(rb + c);
        a.x += rv.x; a.y += rv.y; a.z += rv.z; a.w += rv.w;
      }
      ushort4 hh, ll;
      split2(a.x, hh.x, ll.x); split2(a.y, hh.y, ll.y);
      split2(a.z, hh.z, ll.z); split2(a.w, hh.w, ll.w);
      *(ushort4*)&AS[0][c >> 3][q][c & 7] = hh;
      *(ushort4*)&AS[1][c >> 3][q][c & 7] = ll;
    }
    __syncthreads();

    f32x4 acc[2][4] = {{zed, zed, zed, zed}, {zed, zed, zed, zed}};
    gemm2t64(wcatP, wid * 2, lane, lk, l15, AS, acc);
    f32x4 acc3[4] = {zed, zed, zed, zed};
    if (wid < 2) gemm1t64(wcatP, 16 + wid, lane, lk, l15, AS, acc3);
    __syncthreads();
#pragma unroll
    for (int mf = 0; mf < 2; ++mf) {
      int chb = (wid * 2 + mf) * 16 + lk * 4;
      float4 b4 = *(const float4*)(bcat + chb);
#pragma unroll
      for (int nf = 0; nf < 4; ++nf) {
        int q = nf * 16 + l15;
        float4 o;
        o.x = acc[mf][nf][0] + b4.x; o.y = acc[mf][nf][1] + b4.y;
        o.z = acc[mf][nf][2] + b4.z; o.w = acc[mf][nf][3] + b4.w;
        *(float4*)&ASf[fsi(q, chb)] = o;
      }
    }
    if (wid < 2) {
      int ce = wid * 16 + lk * 4;
      float4 b4 = *(const float4*)(bcat + 256 + ce);
#pragma unroll
      for (int nf = 0; nf < 4; ++nf) {
        int qg = r0 + nf * 16 + l15;
        if (qg < 10000) {
          float4 o;
          o.x = acc3[nf][0] + b4.x; o.y = acc3[nf][1] + b4.y;
          o.z = acc3[nf][2] + b4.z; o.w = acc3[nf][3] + b4.w;
          *(float4*)(oB + (size_t)qg * 32 + ce) = o;
        }
      }
    }
    __syncthreads();
#pragma unroll
    for (int j = 0; j < 8; ++j) {
      int g = t + j * 512;
      int q = g >> 6, c = (g & 63) * 4;
      int qg = r0 + q;
      if (qg < 10000)
        *(float4*)(oA + (size_t)qg * 256 + c) = *(const float4*)&ASf[fsi(q, c)];
    }
  }
}

// ---------------- fused iteration kernel (512 threads, 8 waves, 64 rows/block) ----------------
__global__ __launch_bounds__(512) void fused_iter(
    const float* __restrict__ slots, const float* __restrict__ qin,
    const unsigned short* __restrict__ woutP, const unsigned short* __restrict__ wts1P,
    const unsigned short* __restrict__ w45P,
    const float* __restrict__ bout, const float* __restrict__ bts1,
    const float* __restrict__ bts2,
    float* __restrict__ qout, float* __restrict__ outA, float* __restrict__ outB,
    float* __restrict__ qtmpA, float* __restrict__ qtmpB)
{
  __shared__ __align__(16) unsigned short AS[2][32][64][8]; // 64 KB (time-multiplexed with f32 staging)
  float* ASf = (float*)(&AS[0][0][0][0]);
  int t = threadIdx.x, wid = t >> 6, lane = t & 63, l15 = lane & 15, lk = lane >> 4;
  int r0 = blockIdx.x * 64;
  f32x4 zed = {0.f, 0.f, 0.f, 0.f};

  // ---- phase 0: coalesced stage of slots into AS (split bf16) ----
#pragma unroll
  for (int j = 0; j < 8; ++j) {
    int g = t + j * 512;
    int q = g >> 6, c = (g & 63) * 4;
    int rq = r0 + q; if (rq > 9999) rq = 9999;
    float4 a = *(const float4*)(slots + (size_t)rq * 256 + c);
    ushort4 hh, ll;
    split2(a.x, hh.x, ll.x); split2(a.y, hh.y, ll.y);
    split2(a.z, hh.z, ll.z); split2(a.w, hh.w, ll.w);
    *(ushort4*)&AS[0][c >> 3][q][c & 7] = hh;
    *(ushort4*)&AS[1][c >> 3][q][c & 7] = ll;
  }
  __syncthreads();

  // ---- g2: slots@wout + bout + qin ----
  {
    f32x4 acc[2][4] = {{zed, zed, zed, zed}, {zed, zed, zed, zed}};
    gemm2t64(woutP, wid * 2, lane, lk, l15, AS, acc);
    __syncthreads();   // all AS (slots) reads done
    float4 qreg[8];
#pragma unroll
    for (int j = 0; j < 8; ++j) {
      int g = t + j * 512;
      int q = g >> 6, c = (g & 63) * 4;
      int rq = r0 + q; if (rq > 9999) rq = 9999;
      qreg[j] = *(const float4*)(qin + (size_t)rq * 256 + c);
    }
#pragma unroll
    for (int j = 0; j < 8; ++j) {
      int g = t + j * 512;
      int q = g >> 6, c = (g & 63) * 4;
      *(float4*)&ASf[fsi(q, c)] = qreg[j];
    }
    __syncthreads();
    float4 rr[2][4];
#pragma unroll
    for (int mf = 0; mf < 2; ++mf) {
      int chb = (wid * 2 + mf) * 16 + lk * 4;
#pragma unroll
      for (int nf = 0; nf < 4; ++nf)
        rr[mf][nf] = *(const float4*)&ASf[fsi(nf * 16 + l15, chb)];
    }
    __syncthreads();   // residual reads done; AS can be overwritten
#pragma unroll
    for (int mf = 0; mf < 2; ++mf) {
      int chb = (wid * 2 + mf) * 16 + lk * 4;
      float4 b4 = *(const float4*)(bout + chb);
#pragma unroll
      for (int nf = 0; nf < 4; ++nf) {
        int q = nf * 16 + l15;
        float v0 = acc[mf][nf][0] + b4.x + rr[mf][nf].x;
        float v1 = acc[mf][nf][1] + b4.y + rr[mf][nf].y;
        float v2 = acc[mf][nf][2] + b4.z + rr[mf][nf].z;
        float v3 = acc[mf][nf][3] + b4.w + rr[mf][nf].w;
        ushort4 hh, ll;
        split2(v0, hh.x, ll.x); split2(v1, hh.y, ll.y);
        split2(v2, hh.z, ll.z); split2(v3, hh.w, ll.w);
        *(ushort4*)&AS[0][chb >> 3][q][chb & 7] = hh;
        *(ushort4*)&AS[1][chb >> 3][q][chb & 7] = ll;
      }
    }
    __syncthreads();
  }
  // ---- g3: relu(@wts1 + bts1) ----
  {
    f32x4 acc[2][4] = {{zed, zed, zed, zed}, {zed, zed, zed, zed}};
    gemm2t64(wts1P, wid * 2, lane, lk, l15, AS, acc);
    __syncthreads();
#pragma unroll
    for (int mf = 0; mf < 2; ++mf) {
      int chb = (wid * 2 + mf) * 16 + lk * 4;
      float4 b4 = *(const float4*)(bts1 + chb);
#pragma unroll
      for (int nf = 0; nf < 4; ++nf) {
        int q = nf * 16 + l15;
        float v0 = fmaxf(acc[mf][nf][0] + b4.x, 0.f);
        float v1 = fmaxf(acc[mf][nf][1] + b4.y, 0.f);
        float v2 = fmaxf(acc[mf][nf][2] + b4.z, 0.f);
        float v3 = fmaxf(acc[mf][nf][3] + b4.w, 0.f);
        ushort4 hh, ll;
        split2(v0, hh.x, ll.x); split2(v1, hh.y, ll.y);
        split2(v2, hh.z, ll.z); split2(v3, hh.w, ll.w);
        *(ushort4*)&AS[0][chb >> 3][q][chb & 7] = hh;
        *(ushort4*)&AS[1][chb >> 3][q][chb & 7] = ll;
      }
    }
    __syncthreads();
  }
  // ---- g45: t1 @ w45 (544 cols): qout (0..255) | qtmpA (256..511) | qtmpB (512..543) ----
  {
    f32x4 accA[2][4] = {{zed, zed, zed, zed}, {zed, zed, zed, zed}};
    f32x4 accB[2][4] = {{zed, zed, zed, zed}, {zed, zed, zed, zed}};
    if (wid < 4 || qtmpA) {
      gemm2t64(w45P, wid * 4,     lane, lk, l15, AS, accA);
      gemm2t64(w45P, wid * 4 + 2, lane, lk, l15, AS, accB);
    }
    f32x4 acc3[4] = {zed, zed, zed, zed};
    if (qtmpA && wid < 2) gemm1t64(w45P, 32 + wid, lane, lk, l15, AS, acc3);
    __syncthreads();   // all AS (t1) reads done
    if (wid < 4) {
#pragma unroll
      for (int half = 0; half < 2; ++half) {
#pragma unroll
        for (int mf = 0; mf < 2; ++mf) {
          int chb = (wid * 4 + half * 2 + mf) * 16 + lk * 4;
          float4 b4 = *(const float4*)(bts2 + chb);
#pragma unroll
          for (int nf = 0; nf < 4; ++nf) {
            int q = nf * 16 + l15;
            f32x4 a = half ? accB[mf][nf] : accA[mf][nf];
            float4 o;
            o.x = a[0] + b4.x; o.y = a[1] + b4.y;
            o.z = a[2] + b4.z; o.w = a[3] + b4.w;
            *(float4*)&ASf[fsi(q, chb)] = o;
          }
        }
      }
    }
    if (qtmpA && wid < 2) {
      int ce = wid * 16 + lk * 4;
#pragma unroll
      for (int nf = 0; nf < 4; ++nf) {
        int qg = r0 + nf * 16 + l15;
        if (qg < 10000) {
          float4 o;
          o.x = acc3[nf][0]; o.y = acc3[nf][1]; o.z = acc3[nf][2]; o.w = acc3[nf][3];
          *(float4*)(qtmpB + (size_t)qg * 32 + ce) = o;
        }
      }
    }
    __syncthreads();
#pragma unroll
    for (int j = 0; j < 8; ++j) {
      int g = t + j * 512;
      int q = g >> 6, c = (g & 63) * 4;
      int qg = r0 + q;
      if (qg < 10000) {
        float4 vq = *(const float4*)&ASf[fsi(q, c)];
        size_t go = (size_t)qg * 256 + c;
        *(float4*)(qout + go) = vq;
        if (outA) { *(float4*)(outA + go) = vq; *(float4*)(outB + go) = vq; }
      }
    }
    if (!qtmpA) return;
    __syncthreads();
    if (wid >= 4) {
#pragma unroll
      for (int half = 0; half < 2; ++half) {
#pragma unroll
        for (int mf = 0; mf < 2; ++mf) {
          int cc = ((wid - 4) * 4 + half * 2 + mf) * 16 + lk * 4;
#pragma unroll
          for (int nf = 0; nf < 4; ++nf) {
            int q = nf * 16 + l15;
            f32x4 a = half ? accB[mf][nf] : accA[mf][nf];
            float4 o;
            o.x = a[0]; o.y = a[1]; o.z = a[2]; o.w = a[3];
            *(float4*)&ASf[fsi(q, cc)] = o;
          }
        }
      }
    }
    __syncthreads();
#pragma unroll
    for (int j = 0; j < 8; ++j) {
      int g = t + j * 512;
      int q = g >> 6, c = (g & 63) * 4;
      int qg = r0 + q;
      if (qg < 10000)
        *(float4*)(qtmpA + (size_t)qg * 256 + c) = *(const float4*)&ASf[fsi(q, c)];
    }
  }
}

// ---------------- deformable sampling + attention + cam-average -> slots ----------------
__global__ __launch_bounds__(256) void sca_sample(const float* __restrict__ qtmpA, const float* __restrict__ qtmpB,
                                                  const float* __restrict__ posA, const float* __restrict__ posB,
                                                  const float* __restrict__ V,
                                                  const float* __restrict__ l2i, float* __restrict__ slots)
{
  int b = blockIdx.x;
  int q = (b & 7) * 1250 + (b >> 3);  // XCD-aware: each XCD gets contiguous BEV band
  int t = threadIdx.x;
  int head = t >> 5;
  __shared__ float raw[288];
  __shared__ float attnS[96];
  __shared__ float refx[6][4], refy[6][4];
  __shared__ int mnd[24];
  __shared__ int validn[6];
  __shared__ __align__(16) float w4[576][4];
  __shared__ __align__(16) int o4[576][4];

  {
    float x = qtmpA[(size_t)q * 256 + t];
    if (posA) x += posA[(size_t)q * 256 + t];
    raw[t] = x;
    if (t < 32) {
      float y = qtmpB[(size_t)q * 32 + t];
      if (posB) y += posB[(size_t)q * 32 + t];
      raw[256 + t] = y;
    }
  }
  if (t >= 32 && t < 56) {
    int tt = t - 32;
    int n = tt >> 2, d = tt & 3;
    const float* Mrow = l2i + n * 16;
    int qx = q % 100, qy = q / 100;
    float X = ((qx + 0.5f) / 100.0f) * 102.4f + (-51.2f);
    float Y = ((qy + 0.5f) / 100.0f) * 102.4f + (-51.2f);
    float zi = (d == 3) ? 7.5f : (0.5f + (float)d * (7.0f / 3.0f));
    float Z = zi + (-5.0f);
    float px = Mrow[0] * X + Mrow[1] * Y + Mrow[2] * Z + Mrow[3];
    float py = Mrow[4] * X + Mrow[5] * Y + Mrow[6] * Z + Mrow[7];
    float pz = Mrow[8] * X + Mrow[9] * Y + Mrow[10] * Z + Mrow[11];
    float dz = fmaxf(pz, 1e-5f);
    float xc = (px / dz) / 704.0f;
    float yc = (py / dz) / 256.0f;
    refx[n][d] = xc; refy[n][d] = yc;
    mnd[n * 4 + d] = (pz > 1e-5f) && (xc > 0.f) && (xc < 1.f) && (yc > 0.f) && (yc < 1.f);
  }
  __syncthreads();
  if (t < 8) {
    float mx = raw[192 + t * 12];
    for (int p = 1; p < 12; ++p) mx = fmaxf(mx, raw[192 + t * 12 + p]);
    float s = 0.f;
    float e[12];
#pragma unroll
    for (int p = 0; p < 12; ++p) { e[p] = __expf(raw[192 + t * 12 + p] - mx); s += e[p]; }
    float inv = 1.f / s;
#pragma unroll
    for (int p = 0; p < 12; ++p) attnS[t * 12 + p] = e[p] * inv;
  } else if (t < 14) {
    int n = t - 8;
    validn[n] = mnd[n * 4] | mnd[n * 4 + 1] | mnd[n * 4 + 2] | mnd[n * 4 + 3];
  }
  __syncthreads();

  // compact valid-cam list (bit-packed, uniform across threads)
  int packed = 0, nv = 0;
#pragma unroll
  for (int n = 0; n < 6; ++n)
    if (validn[n]) { packed |= n << (3 * nv); nv++; }
  float invc = 1.f / (float)(nv > 1 ? nv : 1);

  const float WWf[3] = {88.f, 44.f, 22.f}, HHf[3] = {32.f, 16.f, 8.f};
  const int WWi[3] = {88, 44, 22}, STi[3] = {0, 2816, 3520};
  int npts = nv * 96;
  for (int pt = t; pt < npts; pt += 256) {
    int hd = pt & 7;
    int g = pt >> 3;
    int j = g % 12, ni = g / 12;
    int n = (packed >> (3 * ni)) & 7;
    int l = j >> 2, d = j & 3;
    float wwf = WWf[l], hhf = HHf[l];
    int wwi = WWi[l], st = STi[l];
    float a = attnS[hd * 12 + j] * invc;
    float ox = raw[hd * 24 + l * 8 + d * 2 + 0];
    float oy = raw[hd * 24 + l * 8 + d * 2 + 1];
    float x = refx[n][d] * wwf + ox - 0.5f;
    float y = refy[n][d] * hhf + oy - 0.5f;
    float x0 = floorf(x), y0 = floorf(y);
    float fx = x - x0, fy = y - y0;
    float wx0 = 1.f - fx, wy0 = 1.f - fy;
    float vx0 = (x0 >= 0.f && x0 < wwf) ? 1.f : 0.f;
    float vx1 = (x0 + 1.f >= 0.f && x0 + 1.f < wwf) ? 1.f : 0.f;
    float vy0 = (y0 >= 0.f && y0 < hhf) ? 1.f : 0.f;
    float vy1 = (y0 + 1.f >= 0.f && y0 + 1.f < hhf) ? 1.f : 0.f;
    w4[pt][0] = a * wx0 * wy0 * vx0 * vy0;
    w4[pt][1] = a * fx * wy0 * vx1 * vy0;
    w4[pt][2] = a * wx0 * fy * vx0 * vy1;
    w4[pt][3] = a * fx * fy * vx1 * vy1;
    int ix0 = (int)fminf(fmaxf(x0, 0.f), wwf - 1.f);
    int ix1 = (int)fminf(fmaxf(x0 + 1.f, 0.f), wwf - 1.f);
    int iy0 = (int)fminf(fmaxf(y0, 0.f), hhf - 1.f);
    int iy1 = (int)fminf(fmaxf(y0 + 1.f, 0.f), hhf - 1.f);
    // BYTE offsets (row of 256 floats = 1024 B)
    int rA = (st + iy0 * wwi) << 10, rB = (st + iy1 * wwi) << 10;
    o4[pt][0] = rA + (ix0 << 10);
    o4[pt][1] = rA + (ix1 << 10);
    o4[pt][2] = rB + (ix0 << 10);
    o4[pt][3] = rB + (ix1 << 10);
  }
  __syncthreads();

  int t4 = t << 2;
  float acc0 = 0.f, acc1 = 0.f;
  int sl = 0;
#pragma unroll
  for (int n = 0; n < 6; ++n) {
    if (!validn[n]) continue;
    const char* Vn = (const char*)(V + (size_t)n * 946176);  // uniform -> SGPR base
    int pb = sl * 96 + head;
    sl++;
    float va[48];
#pragma unroll
    for (int j = 0; j < 12; ++j) {
      int4 o = *reinterpret_cast<const int4*>(&o4[pb + j * 8][0]);
      va[4 * j + 0] = *(const float*)(Vn + (unsigned)(o.x + t4));
      va[4 * j + 1] = *(const float*)(Vn + (unsigned)(o.y + t4));
      va[4 * j + 2] = *(const float*)(Vn + (unsigned)(o.z + t4));
      va[4 * j + 3] = *(const float*)(Vn + (unsigned)(o.w + t4));
    }
#pragma unroll
    for (int j = 0; j < 12; ++j) {
      float4 w = *reinterpret_cast<const float4*>(&w4[pb + j * 8][0]);
      acc0 = fmaf(w.x, va[4 * j + 0], acc0);
      acc1 = fmaf(w.y, va[4 * j + 1], acc1);
      acc0 = fmaf(w.z, va[4 * j + 2], acc0);
      acc1 = fmaf(w.w, va[4 * j + 3], acc1);
    }
  }
  slots[(size_t)q * 256 + t] = acc0 + acc1;
}

extern "C" void kernel_launch(void* const* d_in, const int* in_sizes, int n_in,
                              void* d_out, int out_size, void* d_ws, size_t ws_size,
                              hipStream_t stream)
{
  const float* imgs = (const float*)d_in[0];
  const float* l2i = (const float*)d_in[1];
  const float* bev_query = (const float*)d_in[2];
  const float* bev_pos = (const float*)d_in[3];
  const float* cams = (const float*)d_in[4];
  const float* lev = (const float*)d_in[5];
  const float* wfpn = (const float*)d_in[6];
  const float* bfpn = (const float*)d_in[7];
  const float* wval = (const float*)d_in[8];
  const float* bval = (const float*)d_in[9];
  const float* woff = (const float*)d_in[10];
  const float* boff = (const float*)d_in[11];
  const float* wattn = (const float*)d_in[12];
  const float* battn = (const float*)d_in[13];
  const float* wout = (const float*)d_in[14];
  const float* bout = (const float*)d_in[15];
  const float* wts1 = (const float*)d_in[16];
  const float* bts1 = (const float*)d_in[17];
  const float* wts2 = (const float*)d_in[18];
  const float* bts2 = (const float*)d_in[19];

  float* W = (float*)d_ws;
  size_t off = 0;
  auto alloc = [&](size_t n) { float* p = W + off; off += n; return p; };
  float* v    = alloc((size_t)2 * 5677056);        // v0 | v1
  float* cur1 = alloc((size_t)12 * 256 * 16 * 44); // 2,162,688
  float* cur2 = alloc((size_t)12 * 256 * 8 * 22);  //   540,672
  float* bqA  = alloc(2560000);
  float* bqB  = alloc(2560000);
  float* qtmpA = alloc(2560000);
  float* qtmpB = alloc(320000);
  float* posA = alloc(2560000);
  float* posB = alloc(320000);
  float* slots = alloc(2560000);
  // coalesced slot-layout weights
  float* wcombPR = alloc(196608);
  float* wcatPR = alloc(73728);
  float* woutPR = alloc(65536);
  float* wts1PR = alloc(65536);
  float* w45PR = alloc(139264);
  float* bcat = alloc(512);
  float* e2 = alloc(4608);
  (void)ws_size; (void)in_sizes; (void)n_in; (void)out_size;

  unsigned short* wcombP = (unsigned short*)wcombPR;
  unsigned short* wcatP = (unsigned short*)wcatPR;
  unsigned short* woutP = (unsigned short*)woutPR;
  unsigned short* wts1P = (unsigned short*)wts1PR;
  unsigned short* w45P = (unsigned short*)w45PR;

  float* v0 = v;
  float* v1 = v + 5677056;
  float* OUT = (float*)d_out;

  // merged pool-level1 + weight prep (independent work, one launch)
  pp<<<8448 + 2130, 256, 0, stream>>>(imgs, cur1,
                                      woff, boff, wattn, battn, wout, wts1, wts2, wfpn, wval,
                                      cams, lev, bfpn, bval,
                                      wcatP, bcat, woutP, wts1P, w45P, wcombP, e2);
  // pool level 2 (depends on cur1)
  pool2x2<<<2112, 256, 0, stream>>>(cur1, cur2, 8, 22, 540672);

  // merged value (both batches) + init (posA/B, qtmpA/B) — independent, concurrent
  vi_fused<<<dim3(58, 6, 3), 512, 0, stream>>>(imgs, cur1, cur2, wcombP, e2, v,
                                               bev_pos, bev_query, bts2, wcatP, bcat,
                                               posA, posB, qtmpA, qtmpB);

  // iter 1
  sca_sample<<<10000, 256, 0, stream>>>(qtmpA, qtmpB, nullptr, nullptr, v0, l2i, slots);
  fused_iter<<<157, 512, 0, stream>>>(slots, bev_query,
      woutP, wts1P, w45P, bout, bts1, bts2,
      bqA, nullptr, nullptr, qtmpA, qtmpB);
  // iter 2 -> ego (bqB + d_out groups 0,1)
  sca_sample<<<10000, 256, 0, stream>>>(qtmpA, qtmpB, posA, posB, v0, l2i, slots);
  fused_iter<<<157, 512, 0, stream>>>(slots, bqA,
      woutP, wts1P, w45P, bout, bts1, bts2,
      bqB, OUT, OUT + 2560000, qtmpA, qtmpB);
  // iter 3 -> nb (directly into d_out)
  sca_sample<<<10000, 256, 0, stream>>>(qtmpA, qtmpB, posA, posB, v1, l2i + 96, slots);
  fused_iter<<<157, 512, 0, stream>>>(slots, bqB,
      woutP, wts1P, w45P, bout, bts1, bts2,
      OUT + 5120000, nullptr, nullptr, nullptr, nullptr);
}

// Round 18
// 273.329 us; speedup vs baseline: 1.0822x; 1.0822x over previous
//
#include <hip/hip_runtime.h>
#include <math.h>

typedef __attribute__((ext_vector_type(8))) short bf16x8;
typedef __attribute__((ext_vector_type(4))) float f32x4;

__device__ __forceinline__ unsigned short f2bf(float x) {
  union { float f; unsigned int u; } v; v.f = x;
  unsigned int r = v.u + 0x7fffu + ((v.u >> 16) & 1u);
  return (unsigned short)(r >> 16);
}
__device__ __forceinline__ float bf2f(unsigned short b) {
  union { unsigned int u; float f; } v; v.u = ((unsigned int)b) << 16; return v.f;
}
__device__ __forceinline__ void split2(float x, unsigned short& h, unsigned short& l) {
  h = f2bf(x);
  l = f2bf(x - bf2f(h));
}
__device__ __forceinline__ int fsi(int q, int c) { return q * 256 + (c ^ ((q & 7) << 2)); }

// direct write into coalesced slot layout: [pair][slot(32)][lane(64)][8us]
__device__ __forceinline__ void writeP(unsigned short* __restrict__ P, int col, int k,
                                       unsigned short h, unsigned short l) {
  int tile = col >> 4;
  int lane = (((k >> 3) & 3) << 4) | (col & 15);
  int ks = k >> 5, j8 = k & 7;
  size_t base = ((size_t)(tile >> 1) * 16384) + (size_t)(((tile & 1) << 4) + ks * 2) * 512
              + (size_t)lane * 8 + j8;
  P[base] = h;
  P[base + 512] = l;
}

// 16 WAVE-COALESCED loads + terminal vmcnt(0) (drains ALL outstanding vmem).
__device__ __forceinline__ void ld16(const unsigned short* b, bf16x8* f) {
  const unsigned short* b1 = b + 2048;
  const unsigned short* b2 = b + 4096;
  const unsigned short* b3 = b + 6144;
  asm volatile(
    "global_load_dwordx4 %0, %16, off\n\t"
    "global_load_dwordx4 %1, %16, off offset:1024\n\t"
    "global_load_dwordx4 %2, %16, off offset:2048\n\t"
    "global_load_dwordx4 %3, %16, off offset:3072\n\t"
    "global_load_dwordx4 %4, %17, off\n\t"
    "global_load_dwordx4 %5, %17, off offset:1024\n\t"
    "global_load_dwordx4 %6, %17, off offset:2048\n\t"
    "global_load_dwordx4 %7, %17, off offset:3072\n\t"
    "global_load_dwordx4 %8, %18, off\n\t"
    "global_load_dwordx4 %9, %18, off offset:1024\n\t"
    "global_load_dwordx4 %10, %18, off offset:2048\n\t"
    "global_load_dwordx4 %11, %18, off offset:3072\n\t"
    "global_load_dwordx4 %12, %19, off\n\t"
    "global_load_dwordx4 %13, %19, off offset:1024\n\t"
    "global_load_dwordx4 %14, %19, off offset:2048\n\t"
    "global_load_dwordx4 %15, %19, off offset:3072\n\t"
    "s_waitcnt vmcnt(0)"
    : "=&v"(f[0]), "=&v"(f[1]), "=&v"(f[2]), "=&v"(f[3]),
      "=&v"(f[4]), "=&v"(f[5]), "=&v"(f[6]), "=&v"(f[7]),
      "=&v"(f[8]), "=&v"(f[9]), "=&v"(f[10]), "=&v"(f[11]),
      "=&v"(f[12]), "=&v"(f[13]), "=&v"(f[14]), "=&v"(f[15])
    : "v"(b), "v"(b1), "v"(b2), "v"(b3));
}

// Same 16 loads, NO wait: valid only after a later ld16's vmcnt(0) + sched_barrier(0).
__device__ __forceinline__ void ld16nw(const unsigned short* b, bf16x8* f) {
  const unsigned short* b1 = b + 2048;
  const unsigned short* b2 = b + 4096;
  const unsigned short* b3 = b + 6144;
  asm volatile(
    "global_load_dwordx4 %0, %16, off\n\t"
    "global_load_dwordx4 %1, %16, off offset:1024\n\t"
    "global_load_dwordx4 %2, %16, off offset:2048\n\t"
    "global_load_dwordx4 %3, %16, off offset:3072\n\t"
    "global_load_dwordx4 %4, %17, off\n\t"
    "global_load_dwordx4 %5, %17, off offset:1024\n\t"
    "global_load_dwordx4 %6, %17, off offset:2048\n\t"
    "global_load_dwordx4 %7, %17, off offset:3072\n\t"
    "global_load_dwordx4 %8, %18, off\n\t"
    "global_load_dwordx4 %9, %18, off offset:1024\n\t"
    "global_load_dwordx4 %10, %18, off offset:2048\n\t"
    "global_load_dwordx4 %11, %18, off offset:3072\n\t"
    "global_load_dwordx4 %12, %19, off\n\t"
    "global_load_dwordx4 %13, %19, off offset:1024\n\t"
    "global_load_dwordx4 %14, %19, off offset:2048\n\t"
    "global_load_dwordx4 %15, %19, off offset:3072"
    : "=&v"(f[0]), "=&v"(f[1]), "=&v"(f[2]), "=&v"(f[3]),
      "=&v"(f[4]), "=&v"(f[5]), "=&v"(f[6]), "=&v"(f[7]),
      "=&v"(f[8]), "=&v"(f[9]), "=&v"(f[10]), "=&v"(f[11]),
      "=&v"(f[12]), "=&v"(f[13]), "=&v"(f[14]), "=&v"(f[15])
    : "v"(b), "v"(b1), "v"(b2), "v"(b3));
}

#define MFMA(a, b, c) __builtin_amdgcn_mfma_f32_16x16x32_bf16(a, b, c, 0, 0, 0)

// ---- 64-row GEMM helpers ----
__device__ __forceinline__ void gemm2t64(
    const unsigned short* __restrict__ Wp, int tile0,
    int lane, int lk, int l15,
    const unsigned short (&AS)[2][32][64][8], f32x4 (&acc)[2][4])
{
  const unsigned short* base = Wp + ((size_t)(tile0 >> 1) * 16384) + (size_t)lane * 8;
  bf16x8 f[32];
  ld16nw(base, f);
  ld16(base + 8192, f + 16);   // vmcnt(0) drains both batches
  __builtin_amdgcn_sched_barrier(0);
#pragma unroll
  for (int ks = 0; ks < 8; ++ks) {
    bf16x8 h0 = f[2 * ks], l0 = f[2 * ks + 1];
    bf16x8 h1 = f[16 + 2 * ks], l1 = f[17 + 2 * ks];
#pragma unroll
    for (int nf = 0; nf < 4; ++nf) {
      bf16x8 bqh = *(const bf16x8*)&AS[0][ks * 4 + lk][nf * 16 + l15][0];
      bf16x8 bql = *(const bf16x8*)&AS[1][ks * 4 + lk][nf * 16 + l15][0];
      acc[0][nf] = MFMA(h0, bqh, acc[0][nf]);
      acc[0][nf] = MFMA(h0, bql, acc[0][nf]);
      acc[0][nf] = MFMA(l0, bqh, acc[0][nf]);
      acc[1][nf] = MFMA(h1, bqh, acc[1][nf]);
      acc[1][nf] = MFMA(h1, bql, acc[1][nf]);
      acc[1][nf] = MFMA(l1, bqh, acc[1][nf]);
    }
  }
}

__device__ __forceinline__ void gemm1t64(
    const unsigned short* __restrict__ Wp, int tile,
    int lane, int lk, int l15,
    const unsigned short (&AS)[2][32][64][8], f32x4 (&acc)[4])
{
  const unsigned short* base = Wp + ((size_t)(tile >> 1) * 16384) + (size_t)(tile & 1) * 8192 + (size_t)lane * 8;
  bf16x8 f[16];
  ld16(base, f);
  __builtin_amdgcn_sched_barrier(0);
#pragma unroll
  for (int ks = 0; ks < 8; ++ks) {
    bf16x8 eh = f[2 * ks], el = f[2 * ks + 1];
#pragma unroll
    for (int nf = 0; nf < 4; ++nf) {
      bf16x8 bqh = *(const bf16x8*)&AS[0][ks * 4 + lk][nf * 16 + l15][0];
      bf16x8 bql = *(const bf16x8*)&AS[1][ks * 4 + lk][nf * 16 + l15][0];
      acc[nf] = MFMA(eh, bqh, acc[nf]);
      acc[nf] = MFMA(eh, bql, acc[nf]);
      acc[nf] = MFMA(el, bqh, acc[nf]);
    }
  }
}

// ---------------- pooling (2x2 mean) ----------------
__global__ __launch_bounds__(256) void pool2x2(const float* __restrict__ in, float* __restrict__ out,
                                               int h, int w, int total)
{
  int i = blockIdx.x * 256 + threadIdx.x;
  if (i >= total) return;
  int x = i % w; int r = i / w; int y = r % h; int ci = r / h;
  const float* p = in + (size_t)ci * (4 * h * w) + (size_t)(2 * y) * (2 * w) + 2 * x;
  out[i] = (p[0] + p[1] + p[2 * w] + p[2 * w + 1]) * 0.25f;
}

// ---------------- weight prep (writes slot layout directly; unrolled k-loops) ----------------
__global__ __launch_bounds__(256) void prep(
    const float* __restrict__ wo, const float* __restrict__ bo,
    const float* __restrict__ wa, const float* __restrict__ ba,
    const float* __restrict__ wout, const float* __restrict__ wts1, const float* __restrict__ wts2,
    const float* __restrict__ wfpn, const float* __restrict__ wval,
    const float* __restrict__ cams, const float* __restrict__ lev,
    const float* __restrict__ bfpn, const float* __restrict__ bval,
    unsigned short* __restrict__ wcatP, float* __restrict__ bcat,
    unsigned short* __restrict__ woutP, unsigned short* __restrict__ wts1P,
    unsigned short* __restrict__ w45P, unsigned short* __restrict__ wcombP,
    float* __restrict__ e2)
{
  int bb = blockIdx.x, t = threadIdx.x;
  if (bb < 768) { // wcomb[l][i][j] = (wfpn[l]@wval)[i][j]; store col=l*256+j, k=i
    int l = bb >> 8, i = bb & 255, j = t;
    const float* a = wfpn + ((size_t)l * 256 + i) * 256;
    float acc = 0.f;
#pragma unroll 8
    for (int k = 0; k < 256; ++k) acc = fmaf(a[k], wval[(size_t)k * 256 + j], acc);
    unsigned short h, lo; split2(acc, h, lo);
    writeP(wcombP, l * 256 + j, i, h, lo);
  } else if (bb < 1056) { // wcat col c, k
    int i = (bb - 768) * 256 + t;
    int c = i >> 8, k = i & 255;
    float v = (c < 192) ? wo[k * 192 + c] : wa[k * 96 + (c - 192)];
    unsigned short h, l; split2(v, h, l);
    writeP(wcatP, c, k, h, l);
    if (i < 288) bcat[i] = (i < 192) ? bo[i] : ba[i - 192];
  } else if (bb < 1312) { // wout^T
    int i = (bb - 1056) * 256 + t;
    int nn = i >> 8, k = i & 255;
    float v = wout[(size_t)k * 256 + nn];
    unsigned short h, l; split2(v, h, l);
    writeP(woutP, nn, k, h, l);
  } else if (bb < 1568) { // wts1^T
    int i = (bb - 1312) * 256 + t;
    int nn = i >> 8, k = i & 255;
    float v = wts1[(size_t)k * 256 + nn];
    unsigned short h, l; split2(v, h, l);
    writeP(wts1P, nn, k, h, l);
  } else if (bb < 1824) { // w45 cols 0..255 = wts2^T
    int i = (bb - 1568) * 256 + t;
    int nn = i >> 8, k = i & 255;
    float v = wts2[(size_t)k * 256 + nn];
    unsigned short h, l; split2(v, h, l);
    writeP(w45P, nn, k, h, l);
  } else if (bb < 2112) { // w45 cols 256..543 = (wts2 @ wcat)^T
    int mp = bb - 1824; // 0..287
    int k = t;
    float acc = 0.f;
#pragma unroll 8
    for (int j = 0; j < 256; ++j) {
      float wc = (mp < 192) ? wo[j * 192 + mp] : wa[j * 96 + (mp - 192)];
      acc = fmaf(wts2[(size_t)k * 256 + j], wc, acc);
    }
    unsigned short h, l; split2(acc, h, l);
    writeP(w45P, 256 + mp, k, h, l);
  } else { // e2
    int e = bb - 2112;
    int n = e / 3, l = e % 3, j = t;
    float acc = bval[j];
#pragma unroll 8
    for (int k = 0; k < 256; ++k) {
      float s = cams[n * 256 + k] + lev[l * 256 + k] + bfpn[l * 256 + k];
      acc = fmaf(s, wval[(size_t)k * 256 + j], acc);
    }
    e2[(size_t)e * 256 + j] = acc;
  }
}

// ---------------- merged value (64 pos/block, z<2) + init (z==2) ----------------
__global__ __launch_bounds__(512) void vi_fused(
    const float* __restrict__ imgs, const float* __restrict__ cur1a, const float* __restrict__ cur2a,
    const unsigned short* __restrict__ wcombP, const float* __restrict__ e2,
    float* __restrict__ Vall,
    const float* __restrict__ bev_pos, const float* __restrict__ bev_query,
    const float* __restrict__ bts2,
    const unsigned short* __restrict__ wcatP, const float* __restrict__ bcat,
    float* __restrict__ posA, float* __restrict__ posB,
    float* __restrict__ qtmpA, float* __restrict__ qtmpB)
{
  __shared__ __align__(16) unsigned short AS[2][32][64][8];  // 64 KB
  float* ASf = (float*)(&AS[0][0][0][0]);
  int t = threadIdx.x, wid = t >> 6, lane = t & 63, l15 = lane & 15, lk = lane >> 4;
  f32x4 zed = {0.f, 0.f, 0.f, 0.f};

  if (blockIdx.z < 2) {
    // ================= VALUE path (64 positions/block) =================
    int bx = blockIdx.x, cam = blockIdx.y, bz = blockIdx.z;
    const float* img0 = imgs + (size_t)bz * 4325376;
    const float* cur1 = cur1a + (size_t)bz * 1081344;
    const float* cur2 = cur2a + (size_t)bz * 270336;
    float* V = Vall + (size_t)bz * 5677056;
    int level, tb, hw; const float* src;
    if (bx < 44)      { level = 0; tb = bx;      hw = 2816; src = img0; }
    else if (bx < 55) { level = 1; tb = bx - 44; hw = 704;  src = cur1; }
    else              { level = 2; tb = bx - 55; hw = 176;  src = cur2; }
    int p0 = tb * 64;
    const int LST[3] = {0, 2816, 3520};
    src += (size_t)cam * 256 * hw;

    { // stage: coalesced scalar reads down k-columns, vector bf16x8 LDS writes
      int pos = t & 63, kg = t >> 6;   // kg 0..7, 32 k each
      bool ok = (p0 + pos) < hw;
      const float* col = src + p0 + pos;
      float vals[32];
#pragma unroll
      for (int i = 0; i < 32; ++i) {
        int k = kg * 32 + i;
        vals[i] = ok ? col[(size_t)k * hw] : 0.f;
      }
#pragma unroll
      for (int qt = 0; qt < 4; ++qt) {
        int ch = kg * 4 + qt;
        bf16x8 hv, lv;
#pragma unroll
        for (int j = 0; j < 8; ++j) {
          unsigned short h, l; split2(vals[qt * 8 + j], h, l);
          hv[j] = (short)h; lv[j] = (short)l;
        }
        *(bf16x8*)&AS[0][ch][pos][0] = hv;
        *(bf16x8*)&AS[1][ch][pos][0] = lv;
      }
    }
    __syncthreads();

    f32x4 acc[2][4] = {{zed, zed, zed, zed}, {zed, zed, zed, zed}};
    gemm2t64(wcombP, level * 16 + wid * 2, lane, lk, l15, AS, acc);
    __syncthreads();

    const float* bias = e2 + (size_t)(cam * 3 + level) * 256;
#pragma unroll
    for (int mf = 0; mf < 2; ++mf) {
      int chb = (wid * 2 + mf) * 16 + lk * 4;
      float4 b4 = *(const float4*)(bias + chb);
#pragma unroll
      for (int nf = 0; nf < 4; ++nf) {
        int q = nf * 16 + l15;
        float4 o;
        o.x = acc[mf][nf][0] + b4.x; o.y = acc[mf][nf][1] + b4.y;
        o.z = acc[mf][nf][2] + b4.z; o.w = acc[mf][nf][3] + b4.w;
        *(float4*)&ASf[fsi(q, chb)] = o;
      }
    }
    __syncthreads();
    float* Vb = V + ((size_t)cam * 3696 + LST[level] + p0) * 256;
#pragma unroll
    for (int j = 0; j < 8; ++j) {
      int g = t + j * 512;
      int q = g >> 6, c = (g & 63) * 4;
      if (p0 + q < hw)
        *(float4*)(Vb + (size_t)q * 256 + c) = *(const float4*)&ASf[fsi(q, c)];
    }
    return;
  }

  // ================= INIT path (z == 2): id = by*58+bx in [0,314) =================
  {
    int id = blockIdx.y * 58 + blockIdx.x;
    if (id >= 314) return;
    int r0 = (id >> 1) * 64;
    int y = id & 1;
    const float* base = y ? bev_query : bev_pos;
    const float* padd = y ? bev_pos : nullptr;
    const float* rb = y ? nullptr : bts2;
    float* oA = y ? qtmpA : posA;
    float* oB = y ? qtmpB : posB;

#pragma unroll
    for (int j = 0; j < 8; ++j) {
      int g = t + j * 512;
      int q = g >> 6, c = (g & 63) * 4;
      int rq = r0 + q; if (rq > 9999) rq = 9999;
      float4 a = *(const float4*)(base + (size_t)rq * 256 + c);
      if (padd) {
        float4 p = *(const float4*)(padd + (size_t)rq * 256 + c);
        a.x += p.x; a.y += p.y; a.z += p.z; a.w += p.w;
      }
      if (rb) {
        float4 rv = *(const float4*)(rb + c);
        a.x += rv.x; a.y += rv.y; a.z += rv.z; a.w += rv.w;
      }
      ushort4 hh, ll;
      split2(a.x, hh.x, ll.x); split2(a.y, hh.y, ll.y);
      split2(a.z, hh.z, ll.z); split2(a.w, hh.w, ll.w);
      *(ushort4*)&AS[0][c >> 3][q][c & 7] = hh;
      *(ushort4*)&AS[1][c >> 3][q][c & 7] = ll;
    }
    __syncthreads();

    f32x4 acc[2][4] = {{zed, zed, zed, zed}, {zed, zed, zed, zed}};
    gemm2t64(wcatP, wid * 2, lane, lk, l15, AS, acc);
    f32x4 acc3[4] = {zed, zed, zed, zed};
    if (wid < 2) gemm1t64(wcatP, 16 + wid, lane, lk, l15, AS, acc3);
    __syncthreads();
#pragma unroll
    for (int mf = 0; mf < 2; ++mf) {
      int chb = (wid * 2 + mf) * 16 + lk * 4;
      float4 b4 = *(const float4*)(bcat + chb);
#pragma unroll
      for (int nf = 0; nf < 4; ++nf) {
        int q = nf * 16 + l15;
        float4 o;
        o.x = acc[mf][nf][0] + b4.x; o.y = acc[mf][nf][1] + b4.y;
        o.z = acc[mf][nf][2] + b4.z; o.w = acc[mf][nf][3] + b4.w;
        *(float4*)&ASf[fsi(q, chb)] = o;
      }
    }
    if (wid < 2) {
      int ce = wid * 16 + lk * 4;
      float4 b4 = *(const float4*)(bcat + 256 + ce);
#pragma unroll
      for (int nf = 0; nf < 4; ++nf) {
        int qg = r0 + nf * 16 + l15;
        if (qg < 10000) {
          float4 o;
          o.x = acc3[nf][0] + b4.x; o.y = acc3[nf][1] + b4.y;
          o.z = acc3[nf][2] + b4.z; o.w = acc3[nf][3] + b4.w;
          *(float4*)(oB + (size_t)qg * 32 + ce) = o;
        }
      }
    }
    __syncthreads();
#pragma unroll
    for (int j = 0; j < 8; ++j) {
      int g = t + j * 512;
      int q = g >> 6, c = (g & 63) * 4;
      int qg = r0 + q;
      if (qg < 10000)
        *(float4*)(oA + (size_t)qg * 256 + c) = *(const float4*)&ASf[fsi(q, c)];
    }
  }
}

// ---------------- fused iteration kernel (512 threads, 8 waves, 64 rows/block) ----------------
__global__ __launch_bounds__(512) void fused_iter(
    const float* __restrict__ slots, const float* __restrict__ qin,
    const unsigned short* __restrict__ woutP, const unsigned short* __restrict__ wts1P,
    const unsigned short* __restrict__ w45P,
    const float* __restrict__ bout, const float* __restrict__ bts1,
    const float* __restrict__ bts2,
    float* __restrict__ qout, float* __restrict__ outA, float* __restrict__ outB,
    float* __restrict__ qtmpA, float* __restrict__ qtmpB)
{
  __shared__ __align__(16) unsigned short AS[2][32][64][8]; // 64 KB (time-multiplexed with f32 staging)
  float* ASf = (float*)(&AS[0][0][0][0]);
  int t = threadIdx.x, wid = t >> 6, lane = t & 63, l15 = lane & 15, lk = lane >> 4;
  int r0 = blockIdx.x * 64;
  f32x4 zed = {0.f, 0.f, 0.f, 0.f};

  // ---- phase 0: coalesced stage of slots into AS (split bf16) ----
#pragma unroll
  for (int j = 0; j < 8; ++j) {
    int g = t + j * 512;
    int q = g >> 6, c = (g & 63) * 4;
    int rq = r0 + q; if (rq > 9999) rq = 9999;
    float4 a = *(const float4*)(slots + (size_t)rq * 256 + c);
    ushort4 hh, ll;
    split2(a.x, hh.x, ll.x); split2(a.y, hh.y, ll.y);
    split2(a.z, hh.z, ll.z); split2(a.w, hh.w, ll.w);
    *(ushort4*)&AS[0][c >> 3][q][c & 7] = hh;
    *(ushort4*)&AS[1][c >> 3][q][c & 7] = ll;
  }
  __syncthreads();

  // ---- g2: slots@wout + bout + qin ----
  {
    f32x4 acc[2][4] = {{zed, zed, zed, zed}, {zed, zed, zed, zed}};
    gemm2t64(woutP, wid * 2, lane, lk, l15, AS, acc);
    __syncthreads();   // all AS (slots) reads done
    float4 qreg[8];
#pragma unroll
    for (int j = 0; j < 8; ++j) {
      int g = t + j * 512;
      int q = g >> 6, c = (g & 63) * 4;
      int rq = r0 + q; if (rq > 9999) rq = 9999;
      qreg[j] = *(const float4*)(qin + (size_t)rq * 256 + c);
    }
#pragma unroll
    for (int j = 0; j < 8; ++j) {
      int g = t + j * 512;
      int q = g >> 6, c = (g & 63) * 4;
      *(float4*)&ASf[fsi(q, c)] = qreg[j];
    }
    __syncthreads();
    float4 rr[2][4];
#pragma unroll
    for (int mf = 0; mf < 2; ++mf) {
      int chb = (wid * 2 + mf) * 16 + lk * 4;
#pragma unroll
      for (int nf = 0; nf < 4; ++nf)
        rr[mf][nf] = *(const float4*)&ASf[fsi(nf * 16 + l15, chb)];
    }
    __syncthreads();   // residual reads done; AS can be overwritten
#pragma unroll
    for (int mf = 0; mf < 2; ++mf) {
      int chb = (wid * 2 + mf) * 16 + lk * 4;
      float4 b4 = *(const float4*)(bout + chb);
#pragma unroll
      for (int nf = 0; nf < 4; ++nf) {
        int q = nf * 16 + l15;
        float v0 = acc[mf][nf][0] + b4.x + rr[mf][nf].x;
        float v1 = acc[mf][nf][1] + b4.y + rr[mf][nf].y;
        float v2 = acc[mf][nf][2] + b4.z + rr[mf][nf].z;
        float v3 = acc[mf][nf][3] + b4.w + rr[mf][nf].w;
        ushort4 hh, ll;
        split2(v0, hh.x, ll.x); split2(v1, hh.y, ll.y);
        split2(v2, hh.z, ll.z); split2(v3, hh.w, ll.w);
        *(ushort4*)&AS[0][chb >> 3][q][chb & 7] = hh;
        *(ushort4*)&AS[1][chb >> 3][q][chb & 7] = ll;
      }
    }
    __syncthreads();
  }
  // ---- g3: relu(@wts1 + bts1) ----
  {
    f32x4 acc[2][4] = {{zed, zed, zed, zed}, {zed, zed, zed, zed}};
    gemm2t64(wts1P, wid * 2, lane, lk, l15, AS, acc);
    __syncthreads();
#pragma unroll
    for (int mf = 0; mf < 2; ++mf) {
      int chb = (wid * 2 + mf) * 16 + lk * 4;
      float4 b4 = *(const float4*)(bts1 + chb);
#pragma unroll
      for (int nf = 0; nf < 4; ++nf) {
        int q = nf * 16 + l15;
        float v0 = fmaxf(acc[mf][nf][0] + b4.x, 0.f);
        float v1 = fmaxf(acc[mf][nf][1] + b4.y, 0.f);
        float v2 = fmaxf(acc[mf][nf][2] + b4.z, 0.f);
        float v3 = fmaxf(acc[mf][nf][3] + b4.w, 0.f);
        ushort4 hh, ll;
        split2(v0, hh.x, ll.x); split2(v1, hh.y, ll.y);
        split2(v2, hh.z, ll.z); split2(v3, hh.w, ll.w);
        *(ushort4*)&AS[0][chb >> 3][q][chb & 7] = hh;
        *(ushort4*)&AS[1][chb >> 3][q][chb & 7] = ll;
      }
    }
    __syncthreads();
  }
  // ---- g45: t1 @ w45 (544 cols): qout (0..255) | qtmpA (256..511) | qtmpB (512..543) ----
  {
    f32x4 accA[2][4] = {{zed, zed, zed, zed}, {zed, zed, zed, zed}};
    f32x4 accB[2][4] = {{zed, zed, zed, zed}, {zed, zed, zed, zed}};
    if (wid < 4 || qtmpA) {
      gemm2t64(w45P, wid * 4,     lane, lk, l15, AS, accA);
      gemm2t64(w45P, wid * 4 + 2, lane, lk, l15, AS, accB);
    }
    f32x4 acc3[4] = {zed, zed, zed, zed};
    if (qtmpA && wid < 2) gemm1t64(w45P, 32 + wid, lane, lk, l15, AS, acc3);
    __syncthreads();   // all AS (t1) reads done
    if (wid < 4) {
#pragma unroll
      for (int half = 0; half < 2; ++half) {
#pragma unroll
        for (int mf = 0; mf < 2; ++mf) {
          int chb = (wid * 4 + half * 2 + mf) * 16 + lk * 4;
          float4 b4 = *(const float4*)(bts2 + chb);
#pragma unroll
          for (int nf = 0; nf < 4; ++nf) {
            int q = nf * 16 + l15;
            f32x4 a = half ? accB[mf][nf] : accA[mf][nf];
            float4 o;
            o.x = a[0] + b4.x; o.y = a[1] + b4.y;
            o.z = a[2] + b4.z; o.w = a[3] + b4.w;
            *(float4*)&ASf[fsi(q, chb)] = o;
          }
        }
      }
    }
    if (qtmpA && wid < 2) {
      int ce = wid * 16 + lk * 4;
#pragma unroll
      for (int nf = 0; nf < 4; ++nf) {
        int qg = r0 + nf * 16 + l15;
        if (qg < 10000) {
          float4 o;
          o.x = acc3[nf][0]; o.y = acc3[nf][1]; o.z = acc3[nf][2]; o.w = acc3[nf][3];
          *(float4*)(qtmpB + (size_t)qg * 32 + ce) = o;
        }
      }
    }
    __syncthreads();
#pragma unroll
    for (int j = 0; j < 8; ++j) {
      int g = t + j * 512;
      int q = g >> 6, c = (g & 63) * 4;
      int qg = r0 + q;
      if (qg < 10000) {
        float4 vq = *(const float4*)&ASf[fsi(q, c)];
        size_t go = (size_t)qg * 256 + c;
        *(float4*)(qout + go) = vq;
        if (outA) { *(float4*)(outA + go) = vq; *(float4*)(outB + go) = vq; }
      }
    }
    if (!qtmpA) return;
    __syncthreads();
    if (wid >= 4) {
#pragma unroll
      for (int half = 0; half < 2; ++half) {
#pragma unroll
        for (int mf = 0; mf < 2; ++mf) {
          int cc = ((wid - 4) * 4 + half * 2 + mf) * 16 + lk * 4;
#pragma unroll
          for (int nf = 0; nf < 4; ++nf) {
            int q = nf * 16 + l15;
            f32x4 a = half ? accB[mf][nf] : accA[mf][nf];
            float4 o;
            o.x = a[0]; o.y = a[1]; o.z = a[2]; o.w = a[3];
            *(float4*)&ASf[fsi(q, cc)] = o;
          }
        }
      }
    }
    __syncthreads();
#pragma unroll
    for (int j = 0; j < 8; ++j) {
      int g = t + j * 512;
      int q = g >> 6, c = (g & 63) * 4;
      int qg = r0 + q;
      if (qg < 10000)
        *(float4*)(qtmpA + (size_t)qg * 256 + c) = *(const float4*)&ASf[fsi(q, c)];
    }
  }
}

// ---------------- deformable sampling + attention + cam-average -> slots ----------------
__global__ __launch_bounds__(256) void sca_sample(const float* __restrict__ qtmpA, const float* __restrict__ qtmpB,
                                                  const float* __restrict__ posA, const float* __restrict__ posB,
                                                  const float* __restrict__ V,
                                                  const float* __restrict__ l2i, float* __restrict__ slots)
{
  int b = blockIdx.x;
  int q = (b & 7) * 1250 + (b >> 3);  // XCD-aware: each XCD gets contiguous BEV band
  int t = threadIdx.x;
  int head = t >> 5;
  __shared__ float raw[288];
  __shared__ float attnS[96];
  __shared__ float refx[6][4], refy[6][4];
  __shared__ int mnd[24];
  __shared__ int validn[6];
  __shared__ __align__(16) float w4[576][4];
  __shared__ __align__(16) int o4[576][4];

  {
    float x = qtmpA[(size_t)q * 256 + t];
    if (posA) x += posA[(size_t)q * 256 + t];
    raw[t] = x;
    if (t < 32) {
      float y = qtmpB[(size_t)q * 32 + t];
      if (posB) y += posB[(size_t)q * 32 + t];
      raw[256 + t] = y;
    }
  }
  if (t >= 32 && t < 56) {
    int tt = t - 32;
    int n = tt >> 2, d = tt & 3;
    const float* Mrow = l2i + n * 16;
    int qx = q % 100, qy = q / 100;
    float X = ((qx + 0.5f) / 100.0f) * 102.4f + (-51.2f);
    float Y = ((qy + 0.5f) / 100.0f) * 102.4f + (-51.2f);
    float zi = (d == 3) ? 7.5f : (0.5f + (float)d * (7.0f / 3.0f));
    float Z = zi + (-5.0f);
    float px = Mrow[0] * X + Mrow[1] * Y + Mrow[2] * Z + Mrow[3];
    float py = Mrow[4] * X + Mrow[5] * Y + Mrow[6] * Z + Mrow[7];
    float pz = Mrow[8] * X + Mrow[9] * Y + Mrow[10] * Z + Mrow[11];
    float dz = fmaxf(pz, 1e-5f);
    float xc = (px / dz) / 704.0f;
    float yc = (py / dz) / 256.0f;
    refx[n][d] = xc; refy[n][d] = yc;
    mnd[n * 4 + d] = (pz > 1e-5f) && (xc > 0.f) && (xc < 1.f) && (yc > 0.f) && (yc < 1.f);
  }
  __syncthreads();
  if (t < 8) {
    float mx = raw[192 + t * 12];
    for (int p = 1; p < 12; ++p) mx = fmaxf(mx, raw[192 + t * 12 + p]);
    float s = 0.f;
    float e[12];
#pragma unroll
    for (int p = 0; p < 12; ++p) { e[p] = __expf(raw[192 + t * 12 + p] - mx); s += e[p]; }
    float inv = 1.f / s;
#pragma unroll
    for (int p = 0; p < 12; ++p) attnS[t * 12 + p] = e[p] * inv;
  } else if (t < 14) {
    int n = t - 8;
    validn[n] = mnd[n * 4] | mnd[n * 4 + 1] | mnd[n * 4 + 2] | mnd[n * 4 + 3];
  }
  __syncthreads();

  // compact valid-cam list (bit-packed, uniform across threads)
  int packed = 0, nv = 0;
#pragma unroll
  for (int n = 0; n < 6; ++n)
    if (validn[n]) { packed |= n << (3 * nv); nv++; }
  float invc = 1.f / (float)(nv > 1 ? nv : 1);

  const float WWf[3] = {88.f, 44.f, 22.f}, HHf[3] = {32.f, 16.f, 8.f};
  const int WWi[3] = {88, 44, 22}, STi[3] = {0, 2816, 3520};
  int npts = nv * 96;
  for (int pt = t; pt < npts; pt += 256) {
    int hd = pt & 7;
    int g = pt >> 3;
    int j = g % 12, ni = g / 12;
    int n = (packed >> (3 * ni)) & 7;
    int l = j >> 2, d = j & 3;
    float wwf = WWf[l], hhf = HHf[l];
    int wwi = WWi[l], st = STi[l];
    float a = attnS[hd * 12 + j] * invc;
    float ox = raw[hd * 24 + l * 8 + d * 2 + 0];
    float oy = raw[hd * 24 + l * 8 + d * 2 + 1];
    float x = refx[n][d] * wwf + ox - 0.5f;
    float y = refy[n][d] * hhf + oy - 0.5f;
    float x0 = floorf(x), y0 = floorf(y);
    float fx = x - x0, fy = y - y0;
    float wx0 = 1.f - fx, wy0 = 1.f - fy;
    float vx0 = (x0 >= 0.f && x0 < wwf) ? 1.f : 0.f;
    float vx1 = (x0 + 1.f >= 0.f && x0 + 1.f < wwf) ? 1.f : 0.f;
    float vy0 = (y0 >= 0.f && y0 < hhf) ? 1.f : 0.f;
    float vy1 = (y0 + 1.f >= 0.f && y0 + 1.f < hhf) ? 1.f : 0.f;
    w4[pt][0] = a * wx0 * wy0 * vx0 * vy0;
    w4[pt][1] = a * fx * wy0 * vx1 * vy0;
    w4[pt][2] = a * wx0 * fy * vx0 * vy1;
    w4[pt][3] = a * fx * fy * vx1 * vy1;
    int ix0 = (int)fminf(fmaxf(x0, 0.f), wwf - 1.f);
    int ix1 = (int)fminf(fmaxf(x0 + 1.f, 0.f), wwf - 1.f);
    int iy0 = (int)fminf(fmaxf(y0, 0.f), hhf - 1.f);
    int iy1 = (int)fminf(fmaxf(y0 + 1.f, 0.f), hhf - 1.f);
    // BYTE offsets (row of 256 floats = 1024 B)
    int rA = (st + iy0 * wwi) << 10, rB = (st + iy1 * wwi) << 10;
    o4[pt][0] = rA + (ix0 << 10);
    o4[pt][1] = rA + (ix1 << 10);
    o4[pt][2] = rB + (ix0 << 10);
    o4[pt][3] = rB + (ix1 << 10);
  }
  __syncthreads();

  int t4 = t << 2;
  float acc0 = 0.f, acc1 = 0.f;
  int sl = 0;
#pragma unroll
  for (int n = 0; n < 6; ++n) {
    if (!validn[n]) continue;
    const char* Vn = (const char*)(V + (size_t)n * 946176);  // uniform -> SGPR base
    int pb = sl * 96 + head;
    sl++;
    float va[48];
#pragma unroll
    for (int j = 0; j < 12; ++j) {
      int4 o = *reinterpret_cast<const int4*>(&o4[pb + j * 8][0]);
      va[4 * j + 0] = *(const float*)(Vn + (unsigned)(o.x + t4));
      va[4 * j + 1] = *(const float*)(Vn + (unsigned)(o.y + t4));
      va[4 * j + 2] = *(const float*)(Vn + (unsigned)(o.z + t4));
      va[4 * j + 3] = *(const float*)(Vn + (unsigned)(o.w + t4));
    }
#pragma unroll
    for (int j = 0; j < 12; ++j) {
      float4 w = *reinterpret_cast<const float4*>(&w4[pb + j * 8][0]);
      acc0 = fmaf(w.x, va[4 * j + 0], acc0);
      acc1 = fmaf(w.y, va[4 * j + 1], acc1);
      acc0 = fmaf(w.z, va[4 * j + 2], acc0);
      acc1 = fmaf(w.w, va[4 * j + 3], acc1);
    }
  }
  slots[(size_t)q * 256 + t] = acc0 + acc1;
}

extern "C" void kernel_launch(void* const* d_in, const int* in_sizes, int n_in,
                              void* d_out, int out_size, void* d_ws, size_t ws_size,
                              hipStream_t stream)
{
  const float* imgs = (const float*)d_in[0];
  const float* l2i = (const float*)d_in[1];
  const float* bev_query = (const float*)d_in[2];
  const float* bev_pos = (const float*)d_in[3];
  const float* cams = (const float*)d_in[4];
  const float* lev = (const float*)d_in[5];
  const float* wfpn = (const float*)d_in[6];
  const float* bfpn = (const float*)d_in[7];
  const float* wval = (const float*)d_in[8];
  const float* bval = (const float*)d_in[9];
  const float* woff = (const float*)d_in[10];
  const float* boff = (const float*)d_in[11];
  const float* wattn = (const float*)d_in[12];
  const float* battn = (const float*)d_in[13];
  const float* wout = (const float*)d_in[14];
  const float* bout = (const float*)d_in[15];
  const float* wts1 = (const float*)d_in[16];
  const float* bts1 = (const float*)d_in[17];
  const float* wts2 = (const float*)d_in[18];
  const float* bts2 = (const float*)d_in[19];

  float* W = (float*)d_ws;
  size_t off = 0;
  auto alloc = [&](size_t n) { float* p = W + off; off += n; return p; };
  float* v    = alloc((size_t)2 * 5677056);        // v0 | v1
  float* cur1 = alloc((size_t)12 * 256 * 16 * 44); // 2,162,688
  float* cur2 = alloc((size_t)12 * 256 * 8 * 22);  //   540,672
  float* bqA  = alloc(2560000);
  float* bqB  = alloc(2560000);
  float* qtmpA = alloc(2560000);
  float* qtmpB = alloc(320000);
  float* posA = alloc(2560000);
  float* posB = alloc(320000);
  float* slots = alloc(2560000);
  // coalesced slot-layout weights
  float* wcombPR = alloc(196608);
  float* wcatPR = alloc(73728);
  float* woutPR = alloc(65536);
  float* wts1PR = alloc(65536);
  float* w45PR = alloc(139264);
  float* bcat = alloc(512);
  float* e2 = alloc(4608);
  (void)ws_size; (void)in_sizes; (void)n_in; (void)out_size;

  unsigned short* wcombP = (unsigned short*)wcombPR;
  unsigned short* wcatP = (unsigned short*)wcatPR;
  unsigned short* woutP = (unsigned short*)woutPR;
  unsigned short* wts1P = (unsigned short*)wts1PR;
  unsigned short* w45P = (unsigned short*)w45PR;

  float* v0 = v;
  float* v1 = v + 5677056;
  float* OUT = (float*)d_out;

  // precompute
  pool2x2<<<8448, 256, 0, stream>>>(imgs, cur1, 16, 44, 2162688);
  pool2x2<<<2112, 256, 0, stream>>>(cur1, cur2, 8, 22, 540672);
  prep<<<2130, 256, 0, stream>>>(woff, boff, wattn, battn, wout, wts1, wts2, wfpn, wval,
                                 cams, lev, bfpn, bval,
                                 wcatP, bcat, woutP, wts1P, w45P, wcombP, e2);

  // merged value (both batches) + init (posA/B, qtmpA/B) — independent, concurrent
  vi_fused<<<dim3(58, 6, 3), 512, 0, stream>>>(imgs, cur1, cur2, wcombP, e2, v,
                                               bev_pos, bev_query, bts2, wcatP, bcat,
                                               posA, posB, qtmpA, qtmpB);

  // iter 1
  sca_sample<<<10000, 256, 0, stream>>>(qtmpA, qtmpB, nullptr, nullptr, v0, l2i, slots);
  fused_iter<<<157, 512, 0, stream>>>(slots, bev_query,
      woutP, wts1P, w45P, bout, bts1, bts2,
      bqA, nullptr, nullptr, qtmpA, qtmpB);
  // iter 2 -> ego (bqB + d_out groups 0,1)
  sca_sample<<<10000, 256, 0, stream>>>(qtmpA, qtmpB, posA, posB, v0, l2i, slots);
  fused_iter<<<157, 512, 0, stream>>>(slots, bqA,
      woutP, wts1P, w45P, bout, bts1, bts2,
      bqB, OUT, OUT + 2560000, qtmpA, qtmpB);
  // iter 3 -> nb (directly into d_out)
  sca_sample<<<10000, 256, 0, stream>>>(qtmpA, qtmpB, posA, posB, v1, l2i + 96, slots);
  fused_iter<<<157, 512, 0, stream>>>(slots, bqB,
      woutP, wts1P, w45P, bout, bts1, bts2,
      OUT + 5120000, nullptr, nullptr, nullptr, nullptr);
}